// Round 1
// 2209.104 us; speedup vs baseline: 4.2445x; 4.2445x over previous
//
#include <hip/hip_runtime.h>

// WindowAttention — Round 1: move QKV + proj GEMMs (94% of FLOPs) onto bf16 MFMA
// with exact-ish truncation-split (hi/lo, 3 products) for fp32-level accuracy.
// Weights pre-converted to fragment-order hi/lo bf16 in d_ws (fallback to the
// previous fp32 kernels if ws_size < 2.3MB).
//
// attn_mfma: block = 1 window, 256 thr (4 waves). 6 passes x 2 heads.
//   Wave (h_l, mhalf) owns C[mhalf*32..+31][head h_l's 96 cols]: 2x6 16x16 tiles.
//   A (x rows) converted in-register from global; B (w frags) 16B loads from ws.
//   Attention core stays fp32 vector, float4-vectorized LDS (odd f4-strides 36/52).
// proj_mfma: block = 64 rows, same split-MFMA, in-place (barrier before writes).

#define NWIN 4096
#define NW_MASK 1024
#define NH 12
#define DIM 384
#define HD 32
#define NT 49
#define SCALEF 0.17677669529663687f

typedef __attribute__((ext_vector_type(4))) float f32x4;
typedef __attribute__((ext_vector_type(8))) __bf16 bf16x8;
typedef __attribute__((ext_vector_type(4))) unsigned int u32x4;

#define MFMA16(A, B, C) __builtin_amdgcn_mfma_f32_16x16x32_bf16( \
    __builtin_bit_cast(bf16x8, A), __builtin_bit_cast(bf16x8, B), (C), 0, 0, 0)

// split fp32 pair -> packed bf16 hi word + packed bf16 lo word (truncation:
// hi = top 16 bits (exact), lo = bf16(x - hi); combined captures 16 mantissa bits)
__device__ __forceinline__ void split2(float x0, float x1, unsigned& h, unsigned& l) {
    unsigned b0 = __float_as_uint(x0), b1 = __float_as_uint(x1);
    unsigned m0 = b0 & 0xffff0000u, m1 = b1 & 0xffff0000u;
    h = m1 | (m0 >> 16);
    float r0 = x0 - __uint_as_float(m0);
    float r1 = x1 - __uint_as_float(m1);
    l = (__float_as_uint(r1) & 0xffff0000u) | (__float_as_uint(r0) >> 16);
}

__device__ __forceinline__ void cvt8(const float4& a, const float4& c,
                                     u32x4& hi, u32x4& lo) {
    unsigned h0, l0, h1, l1, h2, l2, h3, l3;
    split2(a.x, a.y, h0, l0);
    split2(a.z, a.w, h1, l1);
    split2(c.x, c.y, h2, l2);
    split2(c.z, c.w, h3, l3);
    hi = u32x4{h0, h1, h2, h3};
    lo = u32x4{l0, l1, l2, l3};
}

// ---- weight fragment builder: qkv_w (12kt x 72nt) + proj_w (12kt x 24nt) ----
// frag layout: [kt][nt][part(hi/lo)][lane] x 16B ; B elem: col = nt*16+(lane&15),
// k = kt*32 + (lane>>4)*8 + j  (j contiguous in register)
__global__ __launch_bounds__(256)
void conv_w(const float* __restrict__ qkv_w, const float* __restrict__ proj_w,
            u32x4* __restrict__ wf)
{
    int tg = blockIdx.x * 256 + threadIdx.x;     // 288 blocks -> 73728 = 1152 frags x 64
    int fid = tg >> 6, lane = tg & 63;
    int kt = fid / 96, ntc = fid - kt * 96;
    const float* src; int ncols, n; u32x4* dst;
    if (ntc < 72) {
        src = qkv_w; ncols = 3 * DIM; n = ntc * 16 + (lane & 15);
        dst = wf + (size_t)((kt * 72 + ntc) * 128);
    } else {
        int nt2 = ntc - 72;
        src = proj_w; ncols = DIM; n = nt2 * 16 + (lane & 15);
        dst = wf + (size_t)(12 * 72 * 128) + (size_t)((kt * 24 + nt2) * 128);
    }
    int k0 = kt * 32 + ((lane >> 4) << 3);
    float e[8];
    #pragma unroll
    for (int j = 0; j < 8; ++j) e[j] = src[(size_t)(k0 + j) * ncols + n];
    float4 a = make_float4(e[0], e[1], e[2], e[3]);
    float4 c = make_float4(e[4], e[5], e[6], e[7]);
    u32x4 hi, lo; cvt8(a, c, hi, lo);
    dst[lane] = hi; dst[64 + lane] = lo;
}

// ---- fused window attention (QKV via MFMA, attention core fp32 vector) ----
__global__ __launch_bounds__(256, 3)
void attn_mfma(const float* __restrict__ x,
               const float* __restrict__ mask,
               const float* __restrict__ qkv_b,
               const float* __restrict__ rpb,
               const int* __restrict__ rel,
               const u32x4* __restrict__ wf,
               float* __restrict__ y)
{
    __shared__ __align__(16) float qs[2][NT * 36];   // stride 36 fl = 9 f4 (odd -> no bank conflict)
    __shared__ __align__(16) float ks[2][NT * 36];
    __shared__ __align__(16) float vT[2][HD * 52];   // transposed V, stride 52 fl = 13 f4 (odd)
    __shared__ __align__(16) float lg[NT * 52];      // logits/probs, f4-aligned rows

    const int b = blockIdx.x;
    const int t = threadIdx.x;
    const int lane = t & 63;
    const int wid = t >> 6;            // 0..3
    const int h_l = wid >> 1;          // head slot within pass
    const int mhalf = wid & 1;         // row half (0: rows 0-31, 1: rows 32-63)
    const int lrow = lane & 15;
    const int lk8 = (lane >> 4) << 3;
    const int lr4 = (lane >> 4) << 2;
    const float* xb = x + (size_t)b * (NT * DIM);
    const float* mrow = mask + (size_t)(b & (NW_MASK - 1)) * (NT * NT);
    const u32x4* wfl = wf + lane;

    for (int pass = 0; pass < 6; ++pass) {
        const int h = pass * 2 + h_l;
        int gnt[6];                            // global col-tile of qkv_w per ln
        #pragma unroll
        for (int ln = 0; ln < 6; ++ln)
            gnt[ln] = (ln >> 1) * 24 + 2 * h + (ln & 1);

        f32x4 acc[2][6];
        #pragma unroll
        for (int mt = 0; mt < 2; ++mt)
            #pragma unroll
            for (int ln = 0; ln < 6; ++ln)
                acc[mt][ln] = f32x4{0.f, 0.f, 0.f, 0.f};

        for (int kt = 0; kt < 12; ++kt) {
            u32x4 ah[2], al[2];
            #pragma unroll
            for (int mt = 0; mt < 2; ++mt) {
                int row = mhalf * 32 + mt * 16 + lrow;
                float4 a = make_float4(0.f, 0.f, 0.f, 0.f);
                float4 c = make_float4(0.f, 0.f, 0.f, 0.f);
                if (row < NT) {
                    const float4* px = (const float4*)(xb + row * DIM + kt * 32 + lk8);
                    a = px[0]; c = px[1];
                }
                cvt8(a, c, ah[mt], al[mt]);
            }
            #pragma unroll
            for (int ln = 0; ln < 6; ++ln) {
                const u32x4* bp = wfl + (kt * 72 + gnt[ln]) * 128;
                u32x4 bh = bp[0], bl = bp[64];
                #pragma unroll
                for (int mt = 0; mt < 2; ++mt) {
                    acc[mt][ln] = MFMA16(al[mt], bh, acc[mt][ln]);
                    acc[mt][ln] = MFMA16(ah[mt], bl, acc[mt][ln]);
                    acc[mt][ln] = MFMA16(ah[mt], bh, acc[mt][ln]);
                }
            }
        }

        // C scatter: +bias, q pre-scaled, v transposed. C map: col=lane&15,
        // row=(lane>>4)*4+r (m89-verified)
        #pragma unroll
        for (int ln = 0; ln < 6; ++ln) {
            int cc = ln * 16 + lrow;           // 0..95 within head
            int p = cc >> 5, d = cc & 31;
            float bias = qkv_b[p * DIM + h * HD + d];
            #pragma unroll
            for (int mt = 0; mt < 2; ++mt) {
                #pragma unroll
                for (int r = 0; r < 4; ++r) {
                    int row = mhalf * 32 + mt * 16 + lr4 + r;
                    if (row < NT) {
                        float v = acc[mt][ln][r] + bias;
                        if (p == 0)      qs[h_l][row * 36 + d] = v * SCALEF;
                        else if (p == 1) ks[h_l][row * 36 + d] = v;
                        else             vT[h_l][d * 52 + row] = v;
                    }
                }
            }
        }
        __syncthreads();

        for (int hh = 0; hh < 2; ++hh) {
            const int hg = pass * 2 + hh;
            // logits = q.kT + bias + mask
            for (int idx = t; idx < NT * NT; idx += 256) {
                int n = idx / NT, m = idx - n * NT;
                const float4* q4 = (const float4*)&qs[hh][n * 36];
                const float4* k4 = (const float4*)&ks[hh][m * 36];
                float s = 0.f;
                #pragma unroll
                for (int u = 0; u < 8; ++u) {
                    float4 qa = q4[u], ka = k4[u];
                    s += qa.x * ka.x + qa.y * ka.y + qa.z * ka.z + qa.w * ka.w;
                }
                s += rpb[rel[idx] * NH + hg] + mrow[idx];
                lg[n * 52 + m] = s;
            }
            __syncthreads();
            if (t < NT) {                       // softmax, row per thread
                float mx = -1e30f;
                for (int m = 0; m < NT; ++m) mx = fmaxf(mx, lg[t * 52 + m]);
                float sum = 0.f;
                for (int m = 0; m < NT; ++m) {
                    float e = __expf(lg[t * 52 + m] - mx);
                    lg[t * 52 + m] = e; sum += e;
                }
                float inv = 1.f / sum;
                for (int m = 0; m < NT; ++m) lg[t * 52 + m] *= inv;
            }
            __syncthreads();
            // out = P @ V via transposed V
            for (int idx = t; idx < NT * HD; idx += 256) {
                int n = idx >> 5, dd = idx & 31;
                const float4* p4 = (const float4*)&lg[n * 52];
                const float4* v4 = (const float4*)&vT[hh][dd * 52];
                float s = 0.f;
                #pragma unroll
                for (int u = 0; u < 12; ++u) {
                    float4 pa = p4[u], va = v4[u];
                    s += pa.x * va.x + pa.y * va.y + pa.z * va.z + pa.w * va.w;
                }
                s += lg[n * 52 + 48] * vT[hh][dd * 52 + 48];
                y[((size_t)b * NT + n) * DIM + hg * HD + dd] = s;
            }
            __syncthreads();   // protects lg (hh=1) and qs/ks/vT (next pass)
        }
    }
}

// ---- in-place output projection via split-MFMA ----
__global__ __launch_bounds__(256)
void proj_mfma(const u32x4* __restrict__ pwf,
               const float* __restrict__ proj_b,
               float* __restrict__ y)
{
    const int t = threadIdx.x;
    const int lane = t & 63;
    const int wid = t >> 6;
    const int mhalf = wid >> 1, nhalf = wid & 1;
    const int lrow = lane & 15;
    const int lk8 = (lane >> 4) << 3;
    const int lr4 = (lane >> 4) << 2;
    float* yb = y + (size_t)blockIdx.x * (64 * DIM);
    const u32x4* pwl = pwf + lane;

    f32x4 acc[2][12];
    #pragma unroll
    for (int mt = 0; mt < 2; ++mt)
        #pragma unroll
        for (int ln = 0; ln < 12; ++ln)
            acc[mt][ln] = f32x4{0.f, 0.f, 0.f, 0.f};

    for (int kt = 0; kt < 12; ++kt) {
        u32x4 ah[2], al[2];
        #pragma unroll
        for (int mt = 0; mt < 2; ++mt) {
            int row = mhalf * 32 + mt * 16 + lrow;
            const float4* px = (const float4*)(yb + row * DIM + kt * 32 + lk8);
            float4 a = px[0], c = px[1];
            cvt8(a, c, ah[mt], al[mt]);
        }
        #pragma unroll
        for (int ln = 0; ln < 12; ++ln) {
            const u32x4* bp = pwl + (kt * 24 + nhalf * 12 + ln) * 128;
            u32x4 bh = bp[0], bl = bp[64];
            #pragma unroll
            for (int mt = 0; mt < 2; ++mt) {
                acc[mt][ln] = MFMA16(al[mt], bh, acc[mt][ln]);
                acc[mt][ln] = MFMA16(ah[mt], bl, acc[mt][ln]);
                acc[mt][ln] = MFMA16(ah[mt], bh, acc[mt][ln]);
            }
        }
    }
    __syncthreads();   // nhalf-partner wave still reads these rows until here
    #pragma unroll
    for (int ln = 0; ln < 12; ++ln) {
        int col = (nhalf * 12 + ln) * 16 + lrow;
        float bias = proj_b[col];
        #pragma unroll
        for (int mt = 0; mt < 2; ++mt)
            #pragma unroll
            for (int r = 0; r < 4; ++r) {
                int row = mhalf * 32 + mt * 16 + lr4 + r;
                yb[row * DIM + col] = acc[mt][ln][r] + bias;
            }
    }
}

// ================== fallback path (previous fp32 kernels, verbatim) ==================
#define HD_P 33
#define CHUNK 128
#define THREADS_A 384

__global__ __launch_bounds__(THREADS_A)
void win_attn_kernel(const float* __restrict__ x,
                     const float* __restrict__ mask,
                     const float* __restrict__ qkv_w,
                     const float* __restrict__ qkv_b,
                     const float* __restrict__ rpb,
                     const int*   __restrict__ rel,
                     float* __restrict__ y)
{
    __shared__ float xs[NT * CHUNK];
    __shared__ float qs[NT * HD_P];
    __shared__ float ks_[NT * HD_P];
    __shared__ float vs[NT * HD_P];
    __shared__ float lg[NT * NT];

    const int b = blockIdx.x;
    const int t = threadIdx.x;
    const float* xb = x + (size_t)b * (NT * DIM);
    const float* mrow = mask + (size_t)(b & (NW_MASK - 1)) * (NT * NT);

    const int tx = t % 96;
    const int ty = t / 96;
    const int p  = tx / 32;
    const int d  = tx % 32;

    for (int h = 0; h < NH; ++h) {
        float acc[13];
        #pragma unroll
        for (int i = 0; i < 13; ++i) acc[i] = 0.f;
        const int wcol = p * DIM + h * HD + d;

        for (int c = 0; c < 3; ++c) {
            __syncthreads();
            for (int i = t; i < NT * (CHUNK / 4); i += THREADS_A) {
                int r = i >> 5;
                int j = i & 31;
                ((float4*)xs)[i] = ((const float4*)xb)[r * 96 + c * 32 + j];
            }
            __syncthreads();
            const float4* xs4 = (const float4*)xs;
            const float* wb = qkv_w + (size_t)(c * CHUNK) * (3 * DIM) + wcol;
            for (int kk4 = 0; kk4 < CHUNK / 4; ++kk4) {
                float w0 = wb[(size_t)(kk4 * 4 + 0) * (3 * DIM)];
                float w1 = wb[(size_t)(kk4 * 4 + 1) * (3 * DIM)];
                float w2 = wb[(size_t)(kk4 * 4 + 2) * (3 * DIM)];
                float w3 = wb[(size_t)(kk4 * 4 + 3) * (3 * DIM)];
                #pragma unroll
                for (int i = 0; i < 13; ++i) {
                    int r = ty + 4 * i;
                    if (r < NT) {
                        float4 xv = xs4[r * 32 + kk4];
                        acc[i] += xv.x * w0;
                        acc[i] += xv.y * w1;
                        acc[i] += xv.z * w2;
                        acc[i] += xv.w * w3;
                    }
                }
            }
        }
        float bv = qkv_b[wcol];
        float* dst = (p == 0) ? qs : (p == 1) ? ks_ : vs;
        #pragma unroll
        for (int i = 0; i < 13; ++i) {
            int r = ty + 4 * i;
            if (r < NT) dst[r * HD_P + d] = acc[i] + bv;
        }
        __syncthreads();

        for (int idx = t; idx < NT * NT; idx += THREADS_A) {
            int n = idx / NT, m = idx % NT;
            float s = 0.f;
            #pragma unroll
            for (int kk = 0; kk < HD; ++kk)
                s += qs[n * HD_P + kk] * ks_[m * HD_P + kk];
            s = s * SCALEF + rpb[rel[idx] * NH + h] + mrow[idx];
            lg[idx] = s;
        }
        __syncthreads();

        if (t < NT) {
            float mx = -1e30f;
            for (int m = 0; m < NT; ++m) mx = fmaxf(mx, lg[t * NT + m]);
            float sum = 0.f;
            for (int m = 0; m < NT; ++m) {
                float e = __expf(lg[t * NT + m] - mx);
                lg[t * NT + m] = e;
                sum += e;
            }
            float inv = 1.f / sum;
            for (int m = 0; m < NT; ++m) lg[t * NT + m] *= inv;
        }
        __syncthreads();

        for (int idx = t; idx < NT * HD; idx += THREADS_A) {
            int n = idx >> 5, dd = idx & 31;
            float s = 0.f;
            #pragma unroll
            for (int m = 0; m < NT; ++m)
                s += lg[n * NT + m] * vs[m * HD_P + dd];
            y[(size_t)b * (NT * DIM) + n * DIM + h * HD + dd] = s;
        }
    }
}

#define RPB 16
__global__ __launch_bounds__(384)
void proj_kernel(const float* __restrict__ proj_w,
                 const float* __restrict__ proj_b,
                 float* __restrict__ y)
{
    __shared__ float ys[RPB * DIM];
    const int t = threadIdx.x;
    float* base = y + (size_t)blockIdx.x * (RPB * DIM);
    for (int i = t; i < RPB * DIM / 4; i += 384)
        ((float4*)ys)[i] = ((const float4*)base)[i];
    __syncthreads();

    float acc[RPB];
    #pragma unroll
    for (int i = 0; i < RPB; ++i) acc[i] = 0.f;
    const float* wp = proj_w + t;
    const float4* ys4 = (const float4*)ys;
    for (int kk4 = 0; kk4 < DIM / 4; ++kk4) {
        float w0 = wp[(kk4 * 4 + 0) * DIM];
        float w1 = wp[(kk4 * 4 + 1) * DIM];
        float w2 = wp[(kk4 * 4 + 2) * DIM];
        float w3 = wp[(kk4 * 4 + 3) * DIM];
        #pragma unroll
        for (int i = 0; i < RPB; ++i) {
            float4 xv = ys4[i * 96 + kk4];
            acc[i] += xv.x * w0 + xv.y * w1 + xv.z * w2 + xv.w * w3;
        }
    }
    float bv = proj_b[t];
    #pragma unroll
    for (int i = 0; i < RPB; ++i)
        base[i * DIM + t] = acc[i] + bv;
}

// ================== launch ==================
extern "C" void kernel_launch(void* const* d_in, const int* in_sizes, int n_in,
                              void* d_out, int out_size, void* d_ws, size_t ws_size,
                              hipStream_t stream) {
    const float* x      = (const float*)d_in[0];
    const float* mask   = (const float*)d_in[1];
    const float* qkv_w  = (const float*)d_in[2];
    const float* qkv_b  = (const float*)d_in[3];
    const float* proj_w = (const float*)d_in[4];
    const float* proj_b = (const float*)d_in[5];
    const float* rpb    = (const float*)d_in[6];
    const int*   rel    = (const int*)d_in[7];
    float* out = (float*)d_out;

    const size_t WS_NEED = (size_t)(12 * 96 * 128) * 16;   // 2,359,296 B
    if (d_ws != nullptr && ws_size >= WS_NEED) {
        u32x4* wf = (u32x4*)d_ws;
        conv_w<<<288, 256, 0, stream>>>(qkv_w, proj_w, wf);
        attn_mfma<<<NWIN, 256, 0, stream>>>(x, mask, qkv_b, rpb, rel, wf, out);
        proj_mfma<<<(NWIN * NT) / 64, 256, 0, stream>>>(wf + (size_t)(12 * 72 * 128), proj_b, out);
    } else {
        win_attn_kernel<<<NWIN, THREADS_A, 0, stream>>>(x, mask, qkv_w, qkv_b, rpb, rel, out);
        proj_kernel<<<(NWIN * NT) / RPB, 384, 0, stream>>>(proj_w, proj_b, out);
    }
}